// Round 12
// baseline (82.643 us; speedup 1.0000x reference)
//
#include <hip/hip_runtime.h>
#include <math.h>

#define Bn 8
#define NN 200
#define Cc 256
#define RR (Bn*NN)       // 1600 rows total
#define JP 200           // j-stride of transposed nf
#define N_EPS 1e-12f
#define LN_EPS 1e-5f
#define SLOPE 0.01f
#define SCALE 5.0f

#define FMA4(acc, s, v) { acc.x = fmaf((s), (v).x, acc.x); acc.y = fmaf((s), (v).y, acc.y); \
                          acc.z = fmaf((s), (v).z, acc.z); acc.w = fmaf((s), (v).w, acc.w); }

// acc += dot4((a0,a1,a2,a3), wv) — function, not macro (macro form hit the
// parameter-name-vs-member-name token collision: (w).w -> (w1).w1)
__device__ __forceinline__ float dot4acc(float acc, float a0, float a1, float a2, float a3,
                                         float4 wv) {
    return fmaf(a0, wv.x, fmaf(a1, wv.y, fmaf(a2, wv.z, fmaf(a3, wv.w, acc))));
}

// ---------------- reduction helpers ----------------
__device__ __forceinline__ float wave_reduce_sum(float v) {
    #pragma unroll
    for (int o = 32; o > 0; o >>= 1) v += __shfl_xor(v, o);
    return v;
}

// packed two-value reductions over ONE HALF (256 threads) of a 512-thread block.
// sh must hold 16 floats. h = half index (threadIdx.x>>8). ALL 512 threads must call.
__device__ __forceinline__ float2 half_reduce_sum2(float2 v, float* sh, int h) {
    __syncthreads();
    #pragma unroll
    for (int o = 32; o > 0; o >>= 1) { v.x += __shfl_xor(v.x, o); v.y += __shfl_xor(v.y, o); }
    int w = threadIdx.x >> 6;                       // 0..7
    if ((threadIdx.x & 63) == 0) { sh[w*2] = v.x; sh[w*2+1] = v.y; }
    __syncthreads();
    int b0 = h * 8;
    return make_float2(sh[b0]+sh[b0+2]+sh[b0+4]+sh[b0+6],
                       sh[b0+1]+sh[b0+3]+sh[b0+5]+sh[b0+7]);
}

__device__ __forceinline__ float2 half_reduce_max2(float2 v, float* sh, int h) {
    __syncthreads();
    #pragma unroll
    for (int o = 32; o > 0; o >>= 1) {
        v.x = fmaxf(v.x, __shfl_xor(v.x, o));
        v.y = fmaxf(v.y, __shfl_xor(v.y, o));
    }
    int w = threadIdx.x >> 6;
    if ((threadIdx.x & 63) == 0) { sh[w*2] = v.x; sh[w*2+1] = v.y; }
    __syncthreads();
    int b0 = h * 8;
    return make_float2(fmaxf(fmaxf(sh[b0],sh[b0+2]), fmaxf(sh[b0+4],sh[b0+6])),
                       fmaxf(fmaxf(sh[b0+1],sh[b0+3]), fmaxf(sh[b0+5],sh[b0+7])));
}

// ---------------- dispatch 0: 8-row GEMM blocks (256 thr) ----------------
// nb branch: nfT + M = l2norm(lf)@dp_adj_w (TN, W[c][d]).
// else:      P = lf @ dp_aff_w^T (NT, W[d][c]) — no pre-transpose needed.
__global__ void k_pre(const float* __restrict__ lf, const float* __restrict__ dp_adj_w,
                      const float* __restrict__ dp_aff_w,
                      float* __restrict__ nfT, float* __restrict__ M, float* __restrict__ P) {
    __shared__ __align__(16) float sx[8][Cc];    // 8 KB input rows
    __shared__ __align__(16) float buf[8192];    // 32 KB partials [cid][r][qc] float4
    int bid = blockIdx.x;
    int t = threadIdx.x, lane = t & 63, wvi = t >> 6;
    bool nb = bid < RR/8;
    int r0 = (nb ? bid : bid - RR/8) * 8;
    #pragma unroll
    for (int k = 0; k < 2; k++) {
        int r = 2*wvi + k;
        float4 x = ((const float4*)(lf + (size_t)(r0 + r) * Cc))[lane];
        if (nb) {
            float ss = wave_reduce_sum(x.x*x.x + x.y*x.y + x.z*x.z + x.w*x.w);
            float inv = 1.f / fmaxf(sqrtf(ss), N_EPS);
            x.x *= inv; x.y *= inv; x.z *= inv; x.w *= inv;
        }
        ((float4*)&sx[r][0])[lane] = x;
    }
    __syncthreads();
    if (nb) {   // transposed nfT write: column t, 8 consecutive j's
        int b = r0 / NN, i0 = r0 % NN;
        float4 cA, cB;
        cA.x = sx[0][t]; cA.y = sx[1][t]; cA.z = sx[2][t]; cA.w = sx[3][t];
        cB.x = sx[4][t]; cB.y = sx[5][t]; cB.z = sx[6][t]; cB.w = sx[7][t];
        float* np = nfT + (size_t)b * Cc * JP + (size_t)t * JP + i0;
        *((float4*)np) = cA;
        *((float4*)(np + 4)) = cB;
        // TN GEMM: thread (qc col-quad, cid c-chunk of 64)
        int qc = t & 63, cid = t >> 6;
        int c0 = cid * 64;
        float4 z = make_float4(0.f,0.f,0.f,0.f);
        float4 acc0=z, acc1=z, acc2=z, acc3=z, acc4=z, acc5=z, acc6=z, acc7=z;
        #pragma unroll 4
        for (int c4 = c0; c4 < c0 + 64; c4 += 4) {
            float4 w0 = *(const float4*)(dp_adj_w + (size_t)(c4+0) * Cc + 4*qc);
            float4 w1 = *(const float4*)(dp_adj_w + (size_t)(c4+1) * Cc + 4*qc);
            float4 w2 = *(const float4*)(dp_adj_w + (size_t)(c4+2) * Cc + 4*qc);
            float4 w3 = *(const float4*)(dp_adj_w + (size_t)(c4+3) * Cc + 4*qc);
            float4 xr;
            xr = *(const float4*)(&sx[0][c4]);
            FMA4(acc0, xr.x, w0); FMA4(acc0, xr.y, w1); FMA4(acc0, xr.z, w2); FMA4(acc0, xr.w, w3);
            xr = *(const float4*)(&sx[1][c4]);
            FMA4(acc1, xr.x, w0); FMA4(acc1, xr.y, w1); FMA4(acc1, xr.z, w2); FMA4(acc1, xr.w, w3);
            xr = *(const float4*)(&sx[2][c4]);
            FMA4(acc2, xr.x, w0); FMA4(acc2, xr.y, w1); FMA4(acc2, xr.z, w2); FMA4(acc2, xr.w, w3);
            xr = *(const float4*)(&sx[3][c4]);
            FMA4(acc3, xr.x, w0); FMA4(acc3, xr.y, w1); FMA4(acc3, xr.z, w2); FMA4(acc3, xr.w, w3);
            xr = *(const float4*)(&sx[4][c4]);
            FMA4(acc4, xr.x, w0); FMA4(acc4, xr.y, w1); FMA4(acc4, xr.z, w2); FMA4(acc4, xr.w, w3);
            xr = *(const float4*)(&sx[5][c4]);
            FMA4(acc5, xr.x, w0); FMA4(acc5, xr.y, w1); FMA4(acc5, xr.z, w2); FMA4(acc5, xr.w, w3);
            xr = *(const float4*)(&sx[6][c4]);
            FMA4(acc6, xr.x, w0); FMA4(acc6, xr.y, w1); FMA4(acc6, xr.z, w2); FMA4(acc6, xr.w, w3);
            xr = *(const float4*)(&sx[7][c4]);
            FMA4(acc7, xr.x, w0); FMA4(acc7, xr.y, w1); FMA4(acc7, xr.z, w2); FMA4(acc7, xr.w, w3);
        }
        float4* b4 = (float4*)buf;
        int o = cid * 512 + qc;
        b4[o      ] = acc0; b4[o +  64] = acc1; b4[o + 128] = acc2; b4[o + 192] = acc3;
        b4[o + 256] = acc4; b4[o + 320] = acc5; b4[o + 384] = acc6; b4[o + 448] = acc7;
    } else {
        // NT GEMM: thread (qc d-quad, cid c-chunk of 64); W rows d0..d0+3
        int qc = t & 63, cid = t >> 6;
        int c0 = cid * 64, d0 = 4*qc;
        float4 z = make_float4(0.f,0.f,0.f,0.f);
        float4 acc[8] = {z,z,z,z,z,z,z,z};
        #pragma unroll 4
        for (int c4 = c0; c4 < c0 + 64; c4 += 4) {
            float4 w0 = *(const float4*)(dp_aff_w + (size_t)(d0+0) * Cc + c4);
            float4 w1 = *(const float4*)(dp_aff_w + (size_t)(d0+1) * Cc + c4);
            float4 w2 = *(const float4*)(dp_aff_w + (size_t)(d0+2) * Cc + c4);
            float4 w3 = *(const float4*)(dp_aff_w + (size_t)(d0+3) * Cc + c4);
            #pragma unroll
            for (int r = 0; r < 8; r++) {
                float4 xr = *(const float4*)(&sx[r][c4]);
                acc[r].x = dot4acc(acc[r].x, xr.x, xr.y, xr.z, xr.w, w0);
                acc[r].y = dot4acc(acc[r].y, xr.x, xr.y, xr.z, xr.w, w1);
                acc[r].z = dot4acc(acc[r].z, xr.x, xr.y, xr.z, xr.w, w2);
                acc[r].w = dot4acc(acc[r].w, xr.x, xr.y, xr.z, xr.w, w3);
            }
        }
        float4* b4 = (float4*)buf;
        int o = cid * 512 + qc;
        #pragma unroll
        for (int r = 0; r < 8; r++) b4[o + r*64] = acc[r];
    }
    __syncthreads();
    {   // combine 4 c-chunk partials, float4 writes
        float4* b4 = (float4*)buf;
        float* Y = nb ? M : P;
        #pragma unroll
        for (int k = 0; k < 2; k++) {
            int o4 = t + k*256;                  // [0,512): r = o4>>6, qc = o4&63
            int r = o4 >> 6, qc = o4 & 63;
            float4 s0 = b4[o4], s1 = b4[512 + o4], s2 = b4[1024 + o4], s3 = b4[1536 + o4];
            float4 sv;
            sv.x = (s0.x + s1.x) + (s2.x + s3.x);
            sv.y = (s0.y + s1.y) + (s2.y + s3.y);
            sv.z = (s0.z + s1.z) + (s2.z + s3.z);
            sv.w = (s0.w + s1.w) + (s2.w + s3.w);
            *(float4*)(Y + (size_t)(r0 + r) * Cc + 4*qc) = sv;
        }
    }
}

// ---------------- dispatch 1: fused diff_prop rows + stage-2 GEMVs (512 thr, 4 rows) ----------------
// Row ownership: half h owns rows (h, h+2).
__global__ void k_row1f(const float* __restrict__ nfT, const float* __restrict__ Min,
                        const float* __restrict__ P, const float* __restrict__ dp_aff_b,
                        const float* __restrict__ g, const float* __restrict__ bb,
                        const float* __restrict__ fa_adj_w, const float* __restrict__ fa_aff_w,
                        const float* __restrict__ fa_aff_b,
                        float* __restrict__ nfT2, float* __restrict__ M2,
                        float* __restrict__ lf2) {
    __shared__ __align__(16) float smT[Cc*4];    // M rows packed [c][r]
    __shared__ __align__(16) float saraw[4*NN];  // raw A rows [r][j]
    __shared__ __align__(16) float saT[NN*4];    // normalized A packed [j][r]
    __shared__ __align__(16) float suT[Cc*4];    // x1 rows packed [c][r]
    __shared__ __align__(16) float buf[8192];    // 32KB partial-combine union
    __shared__ float sh[16];
    __shared__ float sinv[4];
    int t = threadIdx.x, h = t >> 8, tt = t & 255;
    int b = blockIdx.x & 7;
    int i0 = (blockIdx.x >> 3) * 4;
    size_t base = (size_t)b * NN * Cc;
    {   // pack 4 M rows transposed: smT[c*4+r] = M[i0+r][c]
        const float* src = Min + base + (size_t)i0 * Cc;
        #pragma unroll
        for (int o = t; o < 1024; o += 512) {
            int c = o >> 2, r = o & 3;
            smT[o] = src[(size_t)r * Cc + c];
        }
    }
    __syncthreads();
    // ---- phase A: A[r][j] = sum_c smT[c][r] * nfT[c][j], float4 over j ----
    {
        int q = t & 63, cid = t >> 6;            // j-quad, c-chunk(32)
        if (q < 50) {
            int c0 = cid * 32;
            const float* nfp = nfT + (size_t)b * Cc * JP + (size_t)c0 * JP + 4*q;
            float4 z4 = make_float4(0.f,0.f,0.f,0.f);
            float4 a0 = z4, a1 = z4, a2 = z4, a3 = z4;
            #pragma unroll 8
            for (int c = 0; c < 32; c++) {
                float4 v  = *(const float4*)(nfp + (size_t)c * JP);
                float4 mv = *(const float4*)(&smT[(c0 + c) * 4]);
                FMA4(a0, mv.x, v); FMA4(a1, mv.y, v);
                FMA4(a2, mv.z, v); FMA4(a3, mv.w, v);
            }
            float* pp = buf + cid * 800 + 4*q;   // [cid][r][j]
            *(float4*)(pp      ) = a0;
            *(float4*)(pp + 200) = a1;
            *(float4*)(pp + 400) = a2;
            *(float4*)(pp + 600) = a3;
        }
    }
    __syncthreads();
    for (int o = t; o < 800; o += 512) {         // combine 8 c-chunk partials
        float s = 0.f;
        #pragma unroll
        for (int p = 0; p < 8; p++) s += buf[p*800 + o];
        saraw[o] = s;
    }
    __syncthreads();
    // ---- phase B: exp(5*(a-max)), zero diag, L1 norm; s = sum/max(sum,eps) ----
    int lr0 = h, lr1 = h + 2;
    float2 vm;
    vm.x = (tt < NN) ? saraw[lr0*NN + tt] : -INFINITY;
    vm.y = (tt < NN) ? saraw[lr1*NN + tt] : -INFINITY;
    float2 m = half_reduce_max2(vm, sh, h);
    float e0 = (tt < NN && tt != i0 + lr0) ? expf(SCALE * (vm.x - m.x)) : 0.f;
    float e1 = (tt < NN && tt != i0 + lr1) ? expf(SCALE * (vm.y - m.y)) : 0.f;
    float2 sum = half_reduce_sum2(make_float2(e0, e1), sh, h);
    if (tt < NN) {
        saT[tt*4 + lr0] = e0 / fmaxf(sum.x, N_EPS);
        saT[tt*4 + lr1] = e1 / fmaxf(sum.y, N_EPS);
    }
    float s0 = sum.x / fmaxf(sum.x, N_EPS);
    float s1 = sum.y / fmaxf(sum.y, N_EPS);
    __syncthreads();
    // ---- phase C: U[r][cc] = sum_j saT[j][r] * P[j][cc], float4 over cc ----
    const float* Pb = P + base;
    {
        int qc = t & 63, jc = t >> 6;            // col-quad, j-chunk(25)
        int j0 = jc * 25;
        float4 z4 = make_float4(0.f,0.f,0.f,0.f);
        float4 u0 = z4, u1 = z4, u2 = z4, u3 = z4;
        #pragma unroll 5
        for (int j = j0; j < j0 + 25; j++) {
            float4 pv = *(const float4*)(Pb + (size_t)j * Cc + 4*qc);
            float4 av = *(const float4*)(&saT[j*4]);
            FMA4(u0, av.x, pv); FMA4(u1, av.y, pv);
            FMA4(u2, av.z, pv); FMA4(u3, av.w, pv);
        }
        float* pp = buf + jc*1024 + 4*qc;        // [jc][r][cc]
        *(float4*)(pp      ) = u0;
        *(float4*)(pp + 256) = u1;
        *(float4*)(pp + 512) = u2;
        *(float4*)(pp + 768) = u3;
    }
    __syncthreads();
    float acc0 = 0.f, acc1 = 0.f;                // outputs (lr0,tt)=buf idx t, (lr1,tt)=t+512
    #pragma unroll
    for (int p = 0; p < 8; p++) { acc0 += buf[p*1024 + t]; acc1 += buf[p*1024 + t + 512]; }
    float bv = dp_aff_b[tt];
    float y0 = fmaf(s0, Pb[(size_t)(i0 + lr0) * Cc + tt] + bv, -acc0);
    float y1 = fmaf(s1, Pb[(size_t)(i0 + lr1) * Cc + tt] + bv, -acc1);
    // ---- LayerNorm + LeakyReLU -> x1 (LDS only) ----
    float gg = g[tt], bbv = bb[tt];
    float2 mean2 = half_reduce_sum2(make_float2(y0, y1), sh, h);
    float d0 = y0 - mean2.x * (1.f/256.f);
    float d1 = y1 - mean2.y * (1.f/256.f);
    float2 var2 = half_reduce_sum2(make_float2(d0*d0, d1*d1), sh, h);
    float z0 = d0 / sqrtf(var2.x * (1.f/256.f) + LN_EPS) * gg + bbv;
    float z1 = d1 / sqrtf(var2.y * (1.f/256.f) + LN_EPS) * gg + bbv;
    z0 = (z0 >= 0.f) ? z0 : SLOPE * z0;
    z1 = (z1 >= 0.f) ? z1 : SLOPE * z1;
    suT[tt*4 + lr0] = z0; suT[tt*4 + lr1] = z1;
    float2 ss2 = half_reduce_sum2(make_float2(z0*z0, z1*z1), sh, h);
    if (tt == 0) {
        sinv[lr0] = 1.f / fmaxf(sqrtf(ss2.x), N_EPS);
        sinv[lr1] = 1.f / fmaxf(sqrtf(ss2.y), N_EPS);
    }
    __syncthreads();
    // nf2 transposed write (half 0): float4 over the 4 rows
    if (h == 0) {
        float4 col;
        col.x = suT[tt*4+0] * sinv[0]; col.y = suT[tt*4+1] * sinv[1];
        col.z = suT[tt*4+2] * sinv[2]; col.w = suT[tt*4+3] * sinv[3];
        *((float4*)(nfT2 + (size_t)b * Cc * JP + (size_t)tt * JP + i0)) = col;
    }
    // ---- phase D: both stage-2 GEMVs; mt=0 TN on fa_adj_w, mt=1 NT on fa_aff_w ----
    {
        int qc = t & 63, gidx = t >> 6;
        int mt = gidx & 1, cch = gidx >> 1;      // matrix, c-chunk(64)
        int c0 = cch * 64;
        float4 z4 = make_float4(0.f,0.f,0.f,0.f);
        float4 d0v = z4, d1v = z4, d2v = z4, d3v = z4;
        if (mt == 0) {
            #pragma unroll 8
            for (int c = c0; c < c0 + 64; c++) {
                float4 wv = *(const float4*)(fa_adj_w + (size_t)c * Cc + 4*qc);
                float4 uv = *(const float4*)(&suT[c*4]);
                FMA4(d0v, uv.x, wv); FMA4(d1v, uv.y, wv);
                FMA4(d2v, uv.z, wv); FMA4(d3v, uv.w, wv);
            }
        } else {
            int d0 = 4*qc;
            #pragma unroll 4
            for (int c4 = c0; c4 < c0 + 64; c4 += 4) {
                float4 w0 = *(const float4*)(fa_aff_w + (size_t)(d0+0) * Cc + c4);
                float4 w1 = *(const float4*)(fa_aff_w + (size_t)(d0+1) * Cc + c4);
                float4 w2 = *(const float4*)(fa_aff_w + (size_t)(d0+2) * Cc + c4);
                float4 w3 = *(const float4*)(fa_aff_w + (size_t)(d0+3) * Cc + c4);
                float4 u0 = *(const float4*)(&suT[(c4+0)*4]);
                float4 u1 = *(const float4*)(&suT[(c4+1)*4]);
                float4 u2 = *(const float4*)(&suT[(c4+2)*4]);
                float4 u3 = *(const float4*)(&suT[(c4+3)*4]);
                d0v.x = dot4acc(d0v.x, u0.x, u1.x, u2.x, u3.x, w0);
                d0v.y = dot4acc(d0v.y, u0.x, u1.x, u2.x, u3.x, w1);
                d0v.z = dot4acc(d0v.z, u0.x, u1.x, u2.x, u3.x, w2);
                d0v.w = dot4acc(d0v.w, u0.x, u1.x, u2.x, u3.x, w3);
                d1v.x = dot4acc(d1v.x, u0.y, u1.y, u2.y, u3.y, w0);
                d1v.y = dot4acc(d1v.y, u0.y, u1.y, u2.y, u3.y, w1);
                d1v.z = dot4acc(d1v.z, u0.y, u1.y, u2.y, u3.y, w2);
                d1v.w = dot4acc(d1v.w, u0.y, u1.y, u2.y, u3.y, w3);
                d2v.x = dot4acc(d2v.x, u0.z, u1.z, u2.z, u3.z, w0);
                d2v.y = dot4acc(d2v.y, u0.z, u1.z, u2.z, u3.z, w1);
                d2v.z = dot4acc(d2v.z, u0.z, u1.z, u2.z, u3.z, w2);
                d2v.w = dot4acc(d2v.w, u0.z, u1.z, u2.z, u3.z, w3);
                d3v.x = dot4acc(d3v.x, u0.w, u1.w, u2.w, u3.w, w0);
                d3v.y = dot4acc(d3v.y, u0.w, u1.w, u2.w, u3.w, w1);
                d3v.z = dot4acc(d3v.z, u0.w, u1.w, u2.w, u3.w, w2);
                d3v.w = dot4acc(d3v.w, u0.w, u1.w, u2.w, u3.w, w3);
            }
        }
        float* pp = buf + cch*2048 + mt*1024 + 4*qc;   // [cch][mt][r][cc]
        *(float4*)(pp      ) = d0v;
        *(float4*)(pp + 256) = d1v;
        *(float4*)(pp + 512) = d2v;
        *(float4*)(pp + 768) = d3v;
    }
    __syncthreads();
    {   // float4 combine + writes: o4 = mt*256 + r*64 + qc, cch stride 512 (f4)
        float4* b4 = (float4*)buf;
        int o4 = t;
        int mt2 = o4 >> 8, r2 = (o4 >> 6) & 3, qc2 = o4 & 63;
        float4 v0 = b4[o4], v1 = b4[512 + o4], v2 = b4[1024 + o4], v3 = b4[1536 + o4];
        float4 sv;
        sv.x = (v0.x + v1.x) + (v2.x + v3.x);
        sv.y = (v0.y + v1.y) + (v2.y + v3.y);
        sv.z = (v0.z + v1.z) + (v2.z + v3.z);
        sv.w = (v0.w + v1.w) + (v2.w + v3.w);
        if (mt2 == 0) {
            float sc = sinv[r2];
            sv.x *= sc; sv.y *= sc; sv.z *= sc; sv.w *= sc;
            *(float4*)(M2 + base + (size_t)(i0 + r2) * Cc + 4*qc2) = sv;
        } else {
            float4 fb = *(const float4*)(fa_aff_b + 4*qc2);
            sv.x += fb.x; sv.y += fb.y; sv.z += fb.z; sv.w += fb.w;
            *(float4*)(lf2 + base + (size_t)(i0 + r2) * Cc + 4*qc2) = sv;
        }
    }
}

// ---------------- dispatch 2: feat_aggr rows (512 thr, 4 rows), vectorized ----------------
__global__ void k_row2f(const float* __restrict__ nfT2, const float* __restrict__ M2,
                        const float* __restrict__ lf2, const float* __restrict__ g,
                        const float* __restrict__ bb, float* __restrict__ x2,
                        float* __restrict__ nf3) {
    __shared__ __align__(16) float smT[Cc*4];
    __shared__ __align__(16) float saraw[4*NN];
    __shared__ __align__(16) float saT[NN*4];
    __shared__ __align__(16) float buf[8192];
    __shared__ float sh[16];
    int t = threadIdx.x, h = t >> 8, tt = t & 255;
    int b = blockIdx.x & 7;
    int i0 = (blockIdx.x >> 3) * 4;
    size_t base = (size_t)b * NN * Cc;
    {
        const float* src = M2 + base + (size_t)i0 * Cc;
        #pragma unroll
        for (int o = t; o < 1024; o += 512) {
            int c = o >> 2, r = o & 3;
            smT[o] = src[(size_t)r * Cc + c];
        }
    }
    __syncthreads();
    // phase A
    {
        int q = t & 63, cid = t >> 6;
        if (q < 50) {
            int c0 = cid * 32;
            const float* nfp = nfT2 + (size_t)b * Cc * JP + (size_t)c0 * JP + 4*q;
            float4 z4 = make_float4(0.f,0.f,0.f,0.f);
            float4 a0 = z4, a1 = z4, a2 = z4, a3 = z4;
            #pragma unroll 8
            for (int c = 0; c < 32; c++) {
                float4 v  = *(const float4*)(nfp + (size_t)c * JP);
                float4 mv = *(const float4*)(&smT[(c0 + c) * 4]);
                FMA4(a0, mv.x, v); FMA4(a1, mv.y, v);
                FMA4(a2, mv.z, v); FMA4(a3, mv.w, v);
            }
            float* pp = buf + cid * 800 + 4*q;
            *(float4*)(pp      ) = a0;
            *(float4*)(pp + 200) = a1;
            *(float4*)(pp + 400) = a2;
            *(float4*)(pp + 600) = a3;
        }
    }
    __syncthreads();
    for (int o = t; o < 800; o += 512) {
        float s = 0.f;
        #pragma unroll
        for (int p = 0; p < 8; p++) s += buf[p*800 + o];
        saraw[o] = s;
    }
    __syncthreads();
    // softmax rows (h, h+2)
    int lr0 = h, lr1 = h + 2;
    float2 vm;
    vm.x = (tt < NN) ? saraw[lr0*NN + tt] : -INFINITY;
    vm.y = (tt < NN) ? saraw[lr1*NN + tt] : -INFINITY;
    float2 m = half_reduce_max2(vm, sh, h);
    float e0 = (tt < NN) ? expf(SCALE * (vm.x - m.x)) : 0.f;
    float e1 = (tt < NN) ? expf(SCALE * (vm.y - m.y)) : 0.f;
    float2 sum = half_reduce_sum2(make_float2(e0, e1), sh, h);
    if (tt < NN) { saT[tt*4 + lr0] = e0 / sum.x; saT[tt*4 + lr1] = e1 / sum.y; }
    __syncthreads();
    // phase C: y = A @ lf2
    const float* l2b = lf2 + base;
    {
        int qc = t & 63, jc = t >> 6;
        int j0 = jc * 25;
        float4 z4 = make_float4(0.f,0.f,0.f,0.f);
        float4 u0 = z4, u1 = z4, u2 = z4, u3 = z4;
        #pragma unroll 5
        for (int j = j0; j < j0 + 25; j++) {
            float4 pv = *(const float4*)(l2b + (size_t)j * Cc + 4*qc);
            float4 av = *(const float4*)(&saT[j*4]);
            FMA4(u0, av.x, pv); FMA4(u1, av.y, pv);
            FMA4(u2, av.z, pv); FMA4(u3, av.w, pv);
        }
        float* pp = buf + jc*1024 + 4*qc;
        *(float4*)(pp      ) = u0;
        *(float4*)(pp + 256) = u1;
        *(float4*)(pp + 512) = u2;
        *(float4*)(pp + 768) = u3;
    }
    __syncthreads();
    float y0 = 0.f, y1 = 0.f;
    #pragma unroll
    for (int p = 0; p < 8; p++) { y0 += buf[p*1024 + t]; y1 += buf[p*1024 + t + 512]; }
    // LN + leaky + l2norm epilogue
    float gg = g[tt], bbv = bb[tt];
    float2 mean2 = half_reduce_sum2(make_float2(y0, y1), sh, h);
    float d0 = y0 - mean2.x * (1.f/256.f);
    float d1 = y1 - mean2.y * (1.f/256.f);
    float2 var2 = half_reduce_sum2(make_float2(d0*d0, d1*d1), sh, h);
    float z0 = d0 / sqrtf(var2.x * (1.f/256.f) + LN_EPS) * gg + bbv;
    float z1 = d1 / sqrtf(var2.y * (1.f/256.f) + LN_EPS) * gg + bbv;
    z0 = (z0 >= 0.f) ? z0 : SLOPE * z0;
    z1 = (z1 >= 0.f) ? z1 : SLOPE * z1;
    x2[base + (size_t)(i0 + lr0) * Cc + tt] = z0;
    x2[base + (size_t)(i0 + lr1) * Cc + tt] = z1;
    float2 ss2 = half_reduce_sum2(make_float2(z0*z0, z1*z1), sh, h);
    nf3[base + (size_t)(i0 + lr0) * Cc + tt] = z0 / fmaxf(sqrtf(ss2.x), N_EPS);
    nf3[base + (size_t)(i0 + lr1) * Cc + tt] = z1 / fmaxf(sqrtf(ss2.y), N_EPS);
}

// ---------------- dispatch 3: fused wsum + node_att (4 rows/block, 256 thr) ----------------
__global__ void k_natt(const float* __restrict__ x2, const float* __restrict__ nf3,
                       const float* __restrict__ pos, const float* __restrict__ w,
                       const float* __restrict__ nb, float* __restrict__ out) {
    __shared__ float svb[4][Cc];
    int t = threadIdx.x, lane = t & 63, wv = t >> 6;
    int b = blockIdx.x & 7;
    int i = (blockIdx.x >> 3) * 4 + wv;
    const float4* slab = (const float4*)(nf3 + (size_t)b * NN * Cc);
    float4 acc = make_float4(0.f, 0.f, 0.f, 0.f);
    for (int j = wv * 50; j < wv * 50 + 50; j++) {
        float4 q = slab[j * 64 + lane];
        float wj = w[j];
        acc.x = fmaf(wj, q.x, acc.x);
        acc.y = fmaf(wj, q.y, acc.y);
        acc.z = fmaf(wj, q.z, acc.z);
        acc.w = fmaf(wj, q.w, acc.w);
    }
    ((float4*)&svb[wv][0])[lane] = acc;
    __syncthreads();
    float4 p0 = ((const float4*)&svb[0][0])[lane];
    float4 p1 = ((const float4*)&svb[1][0])[lane];
    float4 p2 = ((const float4*)&svb[2][0])[lane];
    float4 p3 = ((const float4*)&svb[3][0])[lane];
    float4 vb;
    vb.x = (p0.x + p1.x) + (p2.x + p3.x);
    vb.y = (p0.y + p1.y) + (p2.y + p3.y);
    vb.z = (p0.z + p1.z) + (p2.z + p3.z);
    vb.w = (p0.w + p1.w) + (p2.w + p3.w);
    size_t bi = (size_t)b * NN + i;
    float4 nv = ((const float4*)(nf3 + bi * Cc))[lane];
    float val = nv.x*vb.x + nv.y*vb.y + nv.z*vb.z + nv.w*vb.w;
    if (lane < 9) val += pos[bi * 9 + lane] * w[NN + lane];
    val = wave_reduce_sum(val);
    float att = 1.f / (1.f + expf(-(val + nb[0])));
    float4 xo = ((const float4*)(x2 + bi * Cc))[lane];
    xo.x *= att; xo.y *= att; xo.z *= att; xo.w *= att;
    ((float4*)(out + bi * Cc))[lane] = xo;
}

// ---------------- launcher ----------------
extern "C" void kernel_launch(void* const* d_in, const int* in_sizes, int n_in,
                              void* d_out, int out_size, void* d_ws, size_t ws_size,
                              hipStream_t stream) {
    (void)in_sizes; (void)n_in; (void)out_size; (void)ws_size;
    const float* lf       = (const float*)d_in[0];
    const float* pos      = (const float*)d_in[2];
    const float* dp_adj_w = (const float*)d_in[3];
    const float* dp_aff_w = (const float*)d_in[4];
    const float* dp_aff_b = (const float*)d_in[5];
    const float* dp_ln_g  = (const float*)d_in[6];
    const float* dp_ln_b  = (const float*)d_in[7];
    const float* fa_adj_w = (const float*)d_in[8];
    const float* fa_aff_w = (const float*)d_in[9];
    const float* fa_aff_b = (const float*)d_in[10];
    const float* fa_ln_g  = (const float*)d_in[11];
    const float* fa_ln_b  = (const float*)d_in[12];
    const float* na_w     = (const float*)d_in[13];
    const float* na_b     = (const float*)d_in[14];
    float* out = (float*)d_out;
    float* ws  = (float*)d_ws;

    float* nfT  = ws;                    // Bn*Cc*JP
    float* nfT2 = nfT  + Bn * Cc * JP;   // Bn*Cc*JP
    float* M    = nfT2 + Bn * Cc * JP;   // RR*Cc  (M2 written in-place)
    float* P    = M    + RR * Cc;        // RR*Cc
    float* lf2  = P    + RR * Cc;        // RR*Cc
    float* x2   = lf2  + RR * Cc;        // RR*Cc
    float* nf3  = x2   + RR * Cc;        // RR*Cc

    k_pre  <<<RR/8 * 2,   dim3(256), 0, stream>>>(lf, dp_adj_w, dp_aff_w, nfT, M, P);
    k_row1f<<<Bn * NN/4,  dim3(512), 0, stream>>>(nfT, M, P, dp_aff_b, dp_ln_g, dp_ln_b,
                                                  fa_adj_w, fa_aff_w, fa_aff_b, nfT2, M, lf2);
    k_row2f<<<Bn * NN/4,  dim3(512), 0, stream>>>(nfT2, M, lf2, fa_ln_g, fa_ln_b, x2, nf3);
    k_natt <<<Bn * NN/4,  dim3(256), 0, stream>>>(x2, nf3, pos, na_w, na_b, out);
}

// Round 13
// 61.538 us; speedup vs baseline: 1.3430x; 1.3430x over previous
//
#include <hip/hip_runtime.h>
#include <math.h>

#define Bn 8
#define NN 200
#define Cc 256
#define RR (Bn*NN)       // 1600 rows total
#define JP 200           // j-stride of transposed nf
#define N_EPS 1e-12f
#define LN_EPS 1e-5f
#define SLOPE 0.01f
#define SCALE 5.0f

#define FMA4(acc, s, v) { acc.x = fmaf((s), (v).x, acc.x); acc.y = fmaf((s), (v).y, acc.y); \
                          acc.z = fmaf((s), (v).z, acc.z); acc.w = fmaf((s), (v).w, acc.w); }

// ---------------- reduction helpers ----------------
__device__ __forceinline__ float wave_reduce_sum(float v) {
    #pragma unroll
    for (int o = 32; o > 0; o >>= 1) v += __shfl_xor(v, o);
    return v;
}

// packed two-value reductions over ONE HALF (256 threads) of a 512-thread block.
// sh must hold 16 floats. h = half index (threadIdx.x>>8). ALL 512 threads must call.
__device__ __forceinline__ float2 half_reduce_sum2(float2 v, float* sh, int h) {
    __syncthreads();
    #pragma unroll
    for (int o = 32; o > 0; o >>= 1) { v.x += __shfl_xor(v.x, o); v.y += __shfl_xor(v.y, o); }
    int w = threadIdx.x >> 6;                       // 0..7
    if ((threadIdx.x & 63) == 0) { sh[w*2] = v.x; sh[w*2+1] = v.y; }
    __syncthreads();
    int b0 = h * 8;
    return make_float2(sh[b0]+sh[b0+2]+sh[b0+4]+sh[b0+6],
                       sh[b0+1]+sh[b0+3]+sh[b0+5]+sh[b0+7]);
}

__device__ __forceinline__ float2 half_reduce_max2(float2 v, float* sh, int h) {
    __syncthreads();
    #pragma unroll
    for (int o = 32; o > 0; o >>= 1) {
        v.x = fmaxf(v.x, __shfl_xor(v.x, o));
        v.y = fmaxf(v.y, __shfl_xor(v.y, o));
    }
    int w = threadIdx.x >> 6;
    if ((threadIdx.x & 63) == 0) { sh[w*2] = v.x; sh[w*2+1] = v.y; }
    __syncthreads();
    int b0 = h * 8;
    return make_float2(fmaxf(fmaxf(sh[b0],sh[b0+2]), fmaxf(sh[b0+4],sh[b0+6])),
                       fmaxf(fmaxf(sh[b0+1],sh[b0+3]), fmaxf(sh[b0+5],sh[b0+7])));
}

// ---------------- dispatch 0: norm+M blocks (200) + weight-transpose blocks (128) ----------------
// No intra-dispatch dependency: transposes produce WT1/WT2 consumed only by later dispatches.
__global__ void k_pre(const float* __restrict__ lf, const float* __restrict__ dp_adj_w,
                      const float* __restrict__ dp_aff_w, const float* __restrict__ fa_aff_w,
                      float* __restrict__ nfT, float* __restrict__ M,
                      float* __restrict__ WT1, float* __restrict__ WT2) {
    __shared__ __align__(16) float sx[8][Cc];    // 8 KB input rows
    __shared__ __align__(16) float buf[8192];    // 32 KB partials
    __shared__ float tile[32][33];               // transpose staging
    int bid = blockIdx.x;
    int t = threadIdx.x, lane = t & 63, wvi = t >> 6;
    if (bid < RR/8) {
        int r0 = bid * 8;
        #pragma unroll
        for (int k = 0; k < 2; k++) {
            int r = 2*wvi + k;
            float4 x = ((const float4*)(lf + (size_t)(r0 + r) * Cc))[lane];
            float ss = wave_reduce_sum(x.x*x.x + x.y*x.y + x.z*x.z + x.w*x.w);
            float inv = 1.f / fmaxf(sqrtf(ss), N_EPS);
            x.x *= inv; x.y *= inv; x.z *= inv; x.w *= inv;
            ((float4*)&sx[r][0])[lane] = x;
        }
        __syncthreads();
        {   // transposed nfT write: column t, 8 consecutive j's
            int b = r0 / NN, i0 = r0 % NN;
            float4 cA, cB;
            cA.x = sx[0][t]; cA.y = sx[1][t]; cA.z = sx[2][t]; cA.w = sx[3][t];
            cB.x = sx[4][t]; cB.y = sx[5][t]; cB.z = sx[6][t]; cB.w = sx[7][t];
            float* np = nfT + (size_t)b * Cc * JP + (size_t)t * JP + i0;
            *((float4*)np) = cA;
            *((float4*)(np + 4)) = cB;
        }
        // TN GEMM M = nf @ dp_adj_w: thread (qc col-quad, cid c-chunk of 64)
        int qc = t & 63, cid = t >> 6;
        int c0 = cid * 64;
        float4 z = make_float4(0.f,0.f,0.f,0.f);
        float4 acc0=z, acc1=z, acc2=z, acc3=z, acc4=z, acc5=z, acc6=z, acc7=z;
        #pragma unroll 4
        for (int c4 = c0; c4 < c0 + 64; c4 += 4) {
            float4 w0 = *(const float4*)(dp_adj_w + (size_t)(c4+0) * Cc + 4*qc);
            float4 w1 = *(const float4*)(dp_adj_w + (size_t)(c4+1) * Cc + 4*qc);
            float4 w2 = *(const float4*)(dp_adj_w + (size_t)(c4+2) * Cc + 4*qc);
            float4 w3 = *(const float4*)(dp_adj_w + (size_t)(c4+3) * Cc + 4*qc);
            float4 xr;
            xr = *(const float4*)(&sx[0][c4]);
            FMA4(acc0, xr.x, w0); FMA4(acc0, xr.y, w1); FMA4(acc0, xr.z, w2); FMA4(acc0, xr.w, w3);
            xr = *(const float4*)(&sx[1][c4]);
            FMA4(acc1, xr.x, w0); FMA4(acc1, xr.y, w1); FMA4(acc1, xr.z, w2); FMA4(acc1, xr.w, w3);
            xr = *(const float4*)(&sx[2][c4]);
            FMA4(acc2, xr.x, w0); FMA4(acc2, xr.y, w1); FMA4(acc2, xr.z, w2); FMA4(acc2, xr.w, w3);
            xr = *(const float4*)(&sx[3][c4]);
            FMA4(acc3, xr.x, w0); FMA4(acc3, xr.y, w1); FMA4(acc3, xr.z, w2); FMA4(acc3, xr.w, w3);
            xr = *(const float4*)(&sx[4][c4]);
            FMA4(acc4, xr.x, w0); FMA4(acc4, xr.y, w1); FMA4(acc4, xr.z, w2); FMA4(acc4, xr.w, w3);
            xr = *(const float4*)(&sx[5][c4]);
            FMA4(acc5, xr.x, w0); FMA4(acc5, xr.y, w1); FMA4(acc5, xr.z, w2); FMA4(acc5, xr.w, w3);
            xr = *(const float4*)(&sx[6][c4]);
            FMA4(acc6, xr.x, w0); FMA4(acc6, xr.y, w1); FMA4(acc6, xr.z, w2); FMA4(acc6, xr.w, w3);
            xr = *(const float4*)(&sx[7][c4]);
            FMA4(acc7, xr.x, w0); FMA4(acc7, xr.y, w1); FMA4(acc7, xr.z, w2); FMA4(acc7, xr.w, w3);
        }
        float4* b4 = (float4*)buf;
        int o = cid * 512 + qc;
        b4[o      ] = acc0; b4[o +  64] = acc1; b4[o + 128] = acc2; b4[o + 192] = acc3;
        b4[o + 256] = acc4; b4[o + 320] = acc5; b4[o + 384] = acc6; b4[o + 448] = acc7;
        __syncthreads();
        #pragma unroll
        for (int k = 0; k < 2; k++) {
            int o4 = t + k*256;
            int r = o4 >> 6, qc2 = o4 & 63;
            float4 s0 = b4[o4], s1 = b4[512 + o4], s2 = b4[1024 + o4], s3 = b4[1536 + o4];
            float4 sv;
            sv.x = (s0.x + s1.x) + (s2.x + s3.x);
            sv.y = (s0.y + s1.y) + (s2.y + s3.y);
            sv.z = (s0.z + s1.z) + (s2.z + s3.z);
            sv.w = (s0.w + s1.w) + (s2.w + s3.w);
            *(float4*)(M + (size_t)(r0 + r) * Cc + 4*qc2) = sv;
        }
    } else {
        // transpose branch
        int tb = bid - RR/8;
        const float* S; float* D;
        if (tb < 64) { S = dp_aff_w; D = WT1; } else { S = fa_aff_w; D = WT2; tb -= 64; }
        int bx = tb & 7, by = tb >> 3;
        int tx = t & 31, ty = t >> 5;   // ty 0..7
        #pragma unroll
        for (int k = 0; k < 32; k += 8)
            tile[ty + k][tx] = S[(size_t)(by*32 + ty + k) * Cc + bx*32 + tx];
        __syncthreads();
        #pragma unroll
        for (int k = 0; k < 32; k += 8)
            D[(size_t)(bx*32 + ty + k) * Cc + by*32 + tx] = tile[tx][ty + k];
    }
}

// ---------------- dispatch 1: fused diff_prop rows + WT1 GEMV + stage-2 GEMVs ----------------
// 512 thr, 4 rows. Half h owns rows (h, h+2). U = s*lf - A@lf computed on lf;
// W applied per-block via TN GEMV on WT1 (coalesced).
__global__ void k_row1f(const float* __restrict__ nfT, const float* __restrict__ Min,
                        const float* __restrict__ lf, const float* __restrict__ dp_aff_b,
                        const float* __restrict__ WT1,
                        const float* __restrict__ g, const float* __restrict__ bb,
                        const float* __restrict__ fa_adj_w, const float* __restrict__ WT2,
                        const float* __restrict__ fa_aff_b,
                        float* __restrict__ nfT2, float* __restrict__ M2,
                        float* __restrict__ lf2) {
    __shared__ __align__(16) float smT[Cc*4];    // M rows packed [c][r]; reused as U [c][r]
    __shared__ __align__(16) float saraw[4*NN];  // raw A rows [r][j]
    __shared__ __align__(16) float saT[NN*4];    // normalized A packed [j][r]
    __shared__ __align__(16) float suT[Cc*4];    // x1 rows packed [c][r]
    __shared__ __align__(16) float buf[8192];    // 32KB partial-combine union
    __shared__ float sh[16];
    __shared__ float sinv[4];
    int t = threadIdx.x, h = t >> 8, tt = t & 255;
    int b = blockIdx.x & 7;
    int i0 = (blockIdx.x >> 3) * 4;
    size_t base = (size_t)b * NN * Cc;
    {   // pack 4 M rows transposed: smT[c*4+r] = M[i0+r][c]
        const float* src = Min + base + (size_t)i0 * Cc;
        #pragma unroll
        for (int o = t; o < 1024; o += 512) {
            int c = o >> 2, r = o & 3;
            smT[o] = src[(size_t)r * Cc + c];
        }
    }
    __syncthreads();
    // ---- phase A: A[r][j] = sum_c smT[c][r] * nfT[c][j], float4 over j ----
    {
        int q = t & 63, cid = t >> 6;            // j-quad, c-chunk(32)
        if (q < 50) {
            int c0 = cid * 32;
            const float* nfp = nfT + (size_t)b * Cc * JP + (size_t)c0 * JP + 4*q;
            float4 z4 = make_float4(0.f,0.f,0.f,0.f);
            float4 a0 = z4, a1 = z4, a2 = z4, a3 = z4;
            #pragma unroll 8
            for (int c = 0; c < 32; c++) {
                float4 v  = *(const float4*)(nfp + (size_t)c * JP);
                float4 mv = *(const float4*)(&smT[(c0 + c) * 4]);
                FMA4(a0, mv.x, v); FMA4(a1, mv.y, v);
                FMA4(a2, mv.z, v); FMA4(a3, mv.w, v);
            }
            float* pp = buf + cid * 800 + 4*q;   // [cid][r][j]
            *(float4*)(pp      ) = a0;
            *(float4*)(pp + 200) = a1;
            *(float4*)(pp + 400) = a2;
            *(float4*)(pp + 600) = a3;
        }
    }
    __syncthreads();
    for (int o = t; o < 800; o += 512) {         // combine 8 c-chunk partials
        float s = 0.f;
        #pragma unroll
        for (int p = 0; p < 8; p++) s += buf[p*800 + o];
        saraw[o] = s;
    }
    __syncthreads();
    // ---- phase B: exp(5*(a-max)), zero diag, L1 norm; s = sum/max(sum,eps) ----
    int lr0 = h, lr1 = h + 2;
    float2 vm;
    vm.x = (tt < NN) ? saraw[lr0*NN + tt] : -INFINITY;
    vm.y = (tt < NN) ? saraw[lr1*NN + tt] : -INFINITY;
    float2 m = half_reduce_max2(vm, sh, h);
    float e0 = (tt < NN && tt != i0 + lr0) ? expf(SCALE * (vm.x - m.x)) : 0.f;
    float e1 = (tt < NN && tt != i0 + lr1) ? expf(SCALE * (vm.y - m.y)) : 0.f;
    float2 sum = half_reduce_sum2(make_float2(e0, e1), sh, h);
    if (tt < NN) {
        saT[tt*4 + lr0] = e0 / fmaxf(sum.x, N_EPS);
        saT[tt*4 + lr1] = e1 / fmaxf(sum.y, N_EPS);
    }
    float s0 = sum.x / fmaxf(sum.x, N_EPS);
    float s1 = sum.y / fmaxf(sum.y, N_EPS);
    __syncthreads();
    // ---- phase C: U[r][cc] = s*lf_i[cc] - sum_j saT[j][r]*lf[j][cc], float4 over cc ----
    const float* lfb = lf + base;
    {
        int qc = t & 63, jc = t >> 6;            // col-quad, j-chunk(25)
        int j0 = jc * 25;
        float4 z4 = make_float4(0.f,0.f,0.f,0.f);
        float4 u0 = z4, u1 = z4, u2 = z4, u3 = z4;
        #pragma unroll 5
        for (int j = j0; j < j0 + 25; j++) {
            float4 pv = *(const float4*)(lfb + (size_t)j * Cc + 4*qc);
            float4 av = *(const float4*)(&saT[j*4]);
            FMA4(u0, av.x, pv); FMA4(u1, av.y, pv);
            FMA4(u2, av.z, pv); FMA4(u3, av.w, pv);
        }
        float* pp = buf + jc*1024 + 4*qc;        // [jc][r][cc]
        *(float4*)(pp      ) = u0;
        *(float4*)(pp + 256) = u1;
        *(float4*)(pp + 512) = u2;
        *(float4*)(pp + 768) = u3;
    }
    __syncthreads();
    float acc0 = 0.f, acc1 = 0.f;                // (lr0,tt) = buf idx t, (lr1,tt) = t+512
    #pragma unroll
    for (int p = 0; p < 8; p++) { acc0 += buf[p*1024 + t]; acc1 += buf[p*1024 + t + 512]; }
    float U0 = fmaf(s0, lfb[(size_t)(i0 + lr0) * Cc + tt], -acc0);
    float U1 = fmaf(s1, lfb[(size_t)(i0 + lr1) * Cc + tt], -acc1);
    __syncthreads();                             // smT reads long done; safe to overwrite
    smT[tt*4 + lr0] = U0;                        // U packed [c][r]
    smT[tt*4 + lr1] = U1;
    __syncthreads();
    // ---- phase C2: y = U @ WT1 (TN GEMV, coalesced) ----
    {
        int qc = t & 63, cid = t >> 6;           // col-quad, c-chunk(32)
        int c0 = cid * 32;
        float4 z4 = make_float4(0.f,0.f,0.f,0.f);
        float4 p0 = z4, p1 = z4, p2 = z4, p3 = z4;
        #pragma unroll 8
        for (int c = c0; c < c0 + 32; c++) {
            float4 wv = *(const float4*)(WT1 + (size_t)c * Cc + 4*qc);
            float4 uv = *(const float4*)(&smT[c*4]);
            FMA4(p0, uv.x, wv); FMA4(p1, uv.y, wv);
            FMA4(p2, uv.z, wv); FMA4(p3, uv.w, wv);
        }
        float* pp = buf + cid*1024 + 4*qc;       // [cid][r][cc]
        *(float4*)(pp      ) = p0;
        *(float4*)(pp + 256) = p1;
        *(float4*)(pp + 512) = p2;
        *(float4*)(pp + 768) = p3;
    }
    __syncthreads();
    float y0 = 0.f, y1 = 0.f;
    #pragma unroll
    for (int p = 0; p < 8; p++) { y0 += buf[p*1024 + t]; y1 += buf[p*1024 + t + 512]; }
    float bv = dp_aff_b[tt];
    y0 += s0 * bv;
    y1 += s1 * bv;
    // ---- LayerNorm + LeakyReLU -> x1 (LDS only) ----
    float gg = g[tt], bbv = bb[tt];
    float2 mean2 = half_reduce_sum2(make_float2(y0, y1), sh, h);
    float d0 = y0 - mean2.x * (1.f/256.f);
    float d1 = y1 - mean2.y * (1.f/256.f);
    float2 var2 = half_reduce_sum2(make_float2(d0*d0, d1*d1), sh, h);
    float z0 = d0 / sqrtf(var2.x * (1.f/256.f) + LN_EPS) * gg + bbv;
    float z1 = d1 / sqrtf(var2.y * (1.f/256.f) + LN_EPS) * gg + bbv;
    z0 = (z0 >= 0.f) ? z0 : SLOPE * z0;
    z1 = (z1 >= 0.f) ? z1 : SLOPE * z1;
    suT[tt*4 + lr0] = z0; suT[tt*4 + lr1] = z1;
    float2 ss2 = half_reduce_sum2(make_float2(z0*z0, z1*z1), sh, h);
    if (tt == 0) {
        sinv[lr0] = 1.f / fmaxf(sqrtf(ss2.x), N_EPS);
        sinv[lr1] = 1.f / fmaxf(sqrtf(ss2.y), N_EPS);
    }
    __syncthreads();
    // nf2 transposed write (half 0): float4 over the 4 rows
    if (h == 0) {
        float4 col;
        col.x = suT[tt*4+0] * sinv[0]; col.y = suT[tt*4+1] * sinv[1];
        col.z = suT[tt*4+2] * sinv[2]; col.w = suT[tt*4+3] * sinv[3];
        *((float4*)(nfT2 + (size_t)b * Cc * JP + (size_t)tt * JP + i0)) = col;
    }
    // ---- phase D: both stage-2 GEMVs, TN coalesced (fa_adj_w and WT2) ----
    {
        int qc = t & 63, gidx = t >> 6;
        int mt = gidx & 1, cch = gidx >> 1;      // matrix, c-chunk(64)
        const float* Wm = mt ? WT2 : fa_adj_w;
        int c0 = cch * 64;
        float4 z4 = make_float4(0.f,0.f,0.f,0.f);
        float4 d0v = z4, d1v = z4, d2v = z4, d3v = z4;
        #pragma unroll 8
        for (int c = c0; c < c0 + 64; c++) {
            float4 wv = *(const float4*)(Wm + (size_t)c * Cc + 4*qc);
            float4 uv = *(const float4*)(&suT[c*4]);
            FMA4(d0v, uv.x, wv); FMA4(d1v, uv.y, wv);
            FMA4(d2v, uv.z, wv); FMA4(d3v, uv.w, wv);
        }
        float* pp = buf + cch*2048 + mt*1024 + 4*qc;   // [cch][mt][r][cc]
        *(float4*)(pp      ) = d0v;
        *(float4*)(pp + 256) = d1v;
        *(float4*)(pp + 512) = d2v;
        *(float4*)(pp + 768) = d3v;
    }
    __syncthreads();
    {   // float4 combine + writes: o4 = mt*256 + r*64 + qc, cch stride 512 (f4)
        float4* b4 = (float4*)buf;
        int o4 = t;
        int mt2 = o4 >> 8, r2 = (o4 >> 6) & 3, qc2 = o4 & 63;
        float4 v0 = b4[o4], v1 = b4[512 + o4], v2 = b4[1024 + o4], v3 = b4[1536 + o4];
        float4 sv;
        sv.x = (v0.x + v1.x) + (v2.x + v3.x);
        sv.y = (v0.y + v1.y) + (v2.y + v3.y);
        sv.z = (v0.z + v1.z) + (v2.z + v3.z);
        sv.w = (v0.w + v1.w) + (v2.w + v3.w);
        if (mt2 == 0) {
            float sc = sinv[r2];
            sv.x *= sc; sv.y *= sc; sv.z *= sc; sv.w *= sc;
            *(float4*)(M2 + base + (size_t)(i0 + r2) * Cc + 4*qc2) = sv;
        } else {
            float4 fb = *(const float4*)(fa_aff_b + 4*qc2);
            sv.x += fb.x; sv.y += fb.y; sv.z += fb.z; sv.w += fb.w;
            *(float4*)(lf2 + base + (size_t)(i0 + r2) * Cc + 4*qc2) = sv;
        }
    }
}

// ---------------- dispatch 2: feat_aggr rows (512 thr, 4 rows), vectorized ----------------
__global__ void k_row2f(const float* __restrict__ nfT2, const float* __restrict__ M2,
                        const float* __restrict__ lf2, const float* __restrict__ g,
                        const float* __restrict__ bb, float* __restrict__ x2,
                        float* __restrict__ nf3) {
    __shared__ __align__(16) float smT[Cc*4];
    __shared__ __align__(16) float saraw[4*NN];
    __shared__ __align__(16) float saT[NN*4];
    __shared__ __align__(16) float buf[8192];
    __shared__ float sh[16];
    int t = threadIdx.x, h = t >> 8, tt = t & 255;
    int b = blockIdx.x & 7;
    int i0 = (blockIdx.x >> 3) * 4;
    size_t base = (size_t)b * NN * Cc;
    {
        const float* src = M2 + base + (size_t)i0 * Cc;
        #pragma unroll
        for (int o = t; o < 1024; o += 512) {
            int c = o >> 2, r = o & 3;
            smT[o] = src[(size_t)r * Cc + c];
        }
    }
    __syncthreads();
    // phase A
    {
        int q = t & 63, cid = t >> 6;
        if (q < 50) {
            int c0 = cid * 32;
            const float* nfp = nfT2 + (size_t)b * Cc * JP + (size_t)c0 * JP + 4*q;
            float4 z4 = make_float4(0.f,0.f,0.f,0.f);
            float4 a0 = z4, a1 = z4, a2 = z4, a3 = z4;
            #pragma unroll 8
            for (int c = 0; c < 32; c++) {
                float4 v  = *(const float4*)(nfp + (size_t)c * JP);
                float4 mv = *(const float4*)(&smT[(c0 + c) * 4]);
                FMA4(a0, mv.x, v); FMA4(a1, mv.y, v);
                FMA4(a2, mv.z, v); FMA4(a3, mv.w, v);
            }
            float* pp = buf + cid * 800 + 4*q;
            *(float4*)(pp      ) = a0;
            *(float4*)(pp + 200) = a1;
            *(float4*)(pp + 400) = a2;
            *(float4*)(pp + 600) = a3;
        }
    }
    __syncthreads();
    for (int o = t; o < 800; o += 512) {
        float s = 0.f;
        #pragma unroll
        for (int p = 0; p < 8; p++) s += buf[p*800 + o];
        saraw[o] = s;
    }
    __syncthreads();
    // softmax rows (h, h+2)
    int lr0 = h, lr1 = h + 2;
    float2 vm;
    vm.x = (tt < NN) ? saraw[lr0*NN + tt] : -INFINITY;
    vm.y = (tt < NN) ? saraw[lr1*NN + tt] : -INFINITY;
    float2 m = half_reduce_max2(vm, sh, h);
    float e0 = (tt < NN) ? expf(SCALE * (vm.x - m.x)) : 0.f;
    float e1 = (tt < NN) ? expf(SCALE * (vm.y - m.y)) : 0.f;
    float2 sum = half_reduce_sum2(make_float2(e0, e1), sh, h);
    if (tt < NN) { saT[tt*4 + lr0] = e0 / sum.x; saT[tt*4 + lr1] = e1 / sum.y; }
    __syncthreads();
    // phase C: y = A @ lf2
    const float* l2b = lf2 + base;
    {
        int qc = t & 63, jc = t >> 6;
        int j0 = jc * 25;
        float4 z4 = make_float4(0.f,0.f,0.f,0.f);
        float4 u0 = z4, u1 = z4, u2 = z4, u3 = z4;
        #pragma unroll 5
        for (int j = j0; j < j0 + 25; j++) {
            float4 pv = *(const float4*)(l2b + (size_t)j * Cc + 4*qc);
            float4 av = *(const float4*)(&saT[j*4]);
            FMA4(u0, av.x, pv); FMA4(u1, av.y, pv);
            FMA4(u2, av.z, pv); FMA4(u3, av.w, pv);
        }
        float* pp = buf + jc*1024 + 4*qc;
        *(float4*)(pp      ) = u0;
        *(float4*)(pp + 256) = u1;
        *(float4*)(pp + 512) = u2;
        *(float4*)(pp + 768) = u3;
    }
    __syncthreads();
    float y0 = 0.f, y1 = 0.f;
    #pragma unroll
    for (int p = 0; p < 8; p++) { y0 += buf[p*1024 + t]; y1 += buf[p*1024 + t + 512]; }
    // LN + leaky + l2norm epilogue
    float gg = g[tt], bbv = bb[tt];
    float2 mean2 = half_reduce_sum2(make_float2(y0, y1), sh, h);
    float d0 = y0 - mean2.x * (1.f/256.f);
    float d1 = y1 - mean2.y * (1.f/256.f);
    float2 var2 = half_reduce_sum2(make_float2(d0*d0, d1*d1), sh, h);
    float z0 = d0 / sqrtf(var2.x * (1.f/256.f) + LN_EPS) * gg + bbv;
    float z1 = d1 / sqrtf(var2.y * (1.f/256.f) + LN_EPS) * gg + bbv;
    z0 = (z0 >= 0.f) ? z0 : SLOPE * z0;
    z1 = (z1 >= 0.f) ? z1 : SLOPE * z1;
    x2[base + (size_t)(i0 + lr0) * Cc + tt] = z0;
    x2[base + (size_t)(i0 + lr1) * Cc + tt] = z1;
    float2 ss2 = half_reduce_sum2(make_float2(z0*z0, z1*z1), sh, h);
    nf3[base + (size_t)(i0 + lr0) * Cc + tt] = z0 / fmaxf(sqrtf(ss2.x), N_EPS);
    nf3[base + (size_t)(i0 + lr1) * Cc + tt] = z1 / fmaxf(sqrtf(ss2.y), N_EPS);
}

// ---------------- dispatch 3: fused wsum + node_att (4 rows/block, 256 thr) ----------------
__global__ void k_natt(const float* __restrict__ x2, const float* __restrict__ nf3,
                       const float* __restrict__ pos, const float* __restrict__ w,
                       const float* __restrict__ nb, float* __restrict__ out) {
    __shared__ float svb[4][Cc];
    int t = threadIdx.x, lane = t & 63, wv = t >> 6;
    int b = blockIdx.x & 7;
    int i = (blockIdx.x >> 3) * 4 + wv;
    const float4* slab = (const float4*)(nf3 + (size_t)b * NN * Cc);
    float4 acc = make_float4(0.f, 0.f, 0.f, 0.f);
    for (int j = wv * 50; j < wv * 50 + 50; j++) {
        float4 q = slab[j * 64 + lane];
        float wj = w[j];
        acc.x = fmaf(wj, q.x, acc.x);
        acc.y = fmaf(wj, q.y, acc.y);
        acc.z = fmaf(wj, q.z, acc.z);
        acc.w = fmaf(wj, q.w, acc.w);
    }
    ((float4*)&svb[wv][0])[lane] = acc;
    __syncthreads();
    float4 p0 = ((const float4*)&svb[0][0])[lane];
    float4 p1 = ((const float4*)&svb[1][0])[lane];
    float4 p2 = ((const float4*)&svb[2][0])[lane];
    float4 p3 = ((const float4*)&svb[3][0])[lane];
    float4 vb;
    vb.x = (p0.x + p1.x) + (p2.x + p3.x);
    vb.y = (p0.y + p1.y) + (p2.y + p3.y);
    vb.z = (p0.z + p1.z) + (p2.z + p3.z);
    vb.w = (p0.w + p1.w) + (p2.w + p3.w);
    size_t bi = (size_t)b * NN + i;
    float4 nv = ((const float4*)(nf3 + bi * Cc))[lane];
    float val = nv.x*vb.x + nv.y*vb.y + nv.z*vb.z + nv.w*vb.w;
    if (lane < 9) val += pos[bi * 9 + lane] * w[NN + lane];
    val = wave_reduce_sum(val);
    float att = 1.f / (1.f + expf(-(val + nb[0])));
    float4 xo = ((const float4*)(x2 + bi * Cc))[lane];
    xo.x *= att; xo.y *= att; xo.z *= att; xo.w *= att;
    ((float4*)(out + bi * Cc))[lane] = xo;
}

// ---------------- launcher ----------------
extern "C" void kernel_launch(void* const* d_in, const int* in_sizes, int n_in,
                              void* d_out, int out_size, void* d_ws, size_t ws_size,
                              hipStream_t stream) {
    (void)in_sizes; (void)n_in; (void)out_size; (void)ws_size;
    const float* lf       = (const float*)d_in[0];
    const float* pos      = (const float*)d_in[2];
    const float* dp_adj_w = (const float*)d_in[3];
    const float* dp_aff_w = (const float*)d_in[4];
    const float* dp_aff_b = (const float*)d_in[5];
    const float* dp_ln_g  = (const float*)d_in[6];
    const float* dp_ln_b  = (const float*)d_in[7];
    const float* fa_adj_w = (const float*)d_in[8];
    const float* fa_aff_w = (const float*)d_in[9];
    const float* fa_aff_b = (const float*)d_in[10];
    const float* fa_ln_g  = (const float*)d_in[11];
    const float* fa_ln_b  = (const float*)d_in[12];
    const float* na_w     = (const float*)d_in[13];
    const float* na_b     = (const float*)d_in[14];
    float* out = (float*)d_out;
    float* ws  = (float*)d_ws;

    float* nfT  = ws;                    // Bn*Cc*JP
    float* nfT2 = nfT  + Bn * Cc * JP;   // Bn*Cc*JP
    float* M    = nfT2 + Bn * Cc * JP;   // RR*Cc  (M2 written in-place)
    float* lf2  = M    + RR * Cc;        // RR*Cc
    float* x2   = lf2  + RR * Cc;        // RR*Cc
    float* nf3  = x2   + RR * Cc;        // RR*Cc
    float* WT1  = nf3  + RR * Cc;        // Cc*Cc
    float* WT2  = WT1  + Cc * Cc;        // Cc*Cc

    k_pre  <<<RR/8 + 128, dim3(256), 0, stream>>>(lf, dp_adj_w, dp_aff_w, fa_aff_w,
                                                  nfT, M, WT1, WT2);
    k_row1f<<<Bn * NN/4,  dim3(512), 0, stream>>>(nfT, M, lf, dp_aff_b, WT1,
                                                  dp_ln_g, dp_ln_b, fa_adj_w, WT2, fa_aff_b,
                                                  nfT2, M, lf2);
    k_row2f<<<Bn * NN/4,  dim3(512), 0, stream>>>(nfT2, M, lf2, fa_ln_g, fa_ln_b, x2, nf3);
    k_natt <<<Bn * NN/4,  dim3(256), 0, stream>>>(x2, nf3, pos, na_w, na_b, out);
}